// Round 1
// baseline (230.272 us; speedup 1.0000x reference)
//
#include <hip/hip_runtime.h>
#include <math.h>

// ---- problem constants ----
#define NCAMS 6
#define BH_ 100
#define BW_ 100
#define CDIM 256
#define HG_ 100
#define WG_ 40
#define NQ_ 4000           // HG*WG
#define HF_ 48
#define WF_ 80
#define HEADS_ 8
#define PTS_ 8
#define HD_ 32
#define HWV (HF_*WF_)      // 3840
#define M1_ (NCAMS*HWV)    // 23040 rows of value proj
#define M2_ (NCAMS*NQ_)    // 24000 rebatched queries
#define NOUT_ 10000        // BH*BW

#define AT_STRIDE 20       // padded LDS A-tile row stride (floats), 16B-aligned, 8-way max conflict

// 4x4 outer-product microkernel update: a = 4 rows, b = 4 cols
#define MK16(acc, a, b) \
  acc[0][0] += a.x*b.x; acc[0][1] += a.x*b.y; acc[0][2] += a.x*b.z; acc[0][3] += a.x*b.w; \
  acc[1][0] += a.y*b.x; acc[1][1] += a.y*b.y; acc[1][2] += a.y*b.z; acc[1][3] += a.y*b.w; \
  acc[2][0] += a.z*b.x; acc[2][1] += a.z*b.y; acc[2][2] += a.z*b.z; acc[2][3] += a.z*b.w; \
  acc[3][0] += a.w*b.x; acc[3][1] += a.w*b.y; acc[3][2] += a.w*b.z; acc[3][3] += a.w*b.w;

// K0: Wcomb[256][192] = [Woff | Watt]
__global__ __launch_bounds__(256) void k0_wcomb(const float* __restrict__ Woff,
                                                const float* __restrict__ Watt,
                                                float* __restrict__ Wcomb) {
    int idx = blockIdx.x * 256 + threadIdx.x;
    if (idx >= 256 * 192) return;
    int k = idx / 192, j = idx - k * 192;
    Wcomb[idx] = (j < 128) ? Woff[k * 128 + j] : Watt[k * 64 + (j - 128)];
}

// K1: v = value(cam-major rows) @ Wv + bv, scattered to vh[cam][head][hf*WF+wf][hd]
__global__ __launch_bounds__(256) void k1_vproj(const float* __restrict__ value,
                                                const float* __restrict__ Wv,
                                                const float* __restrict__ bv,
                                                float* __restrict__ vh) {
    __shared__ __align__(16) float At[CDIM * AT_STRIDE];
    const int m0 = blockIdx.x * 16;           // row = cam*3840 + hw, never crosses cam (3840%16==0)
    const int cam = m0 / HWV;
    const int hw0 = m0 - cam * HWV;
    for (int idx = threadIdx.x; idx < 16 * CDIM; idx += 256) {
        int r = idx >> 8, c = idx & 255;
        At[c * AT_STRIDE + r] = value[((hw0 + r) * NCAMS + cam) * CDIM + c];
    }
    __syncthreads();
    const int rq = threadIdx.x >> 6;          // 0..3 (row quad)
    const int jq = threadIdx.x & 63;          // 0..63 (col quad)
    float acc[4][4] = {};
    const float4* At4 = (const float4*)At;    // row k at float4 index k*5
    const float4* Wv4 = (const float4*)Wv;
#pragma unroll 4
    for (int k = 0; k < CDIM; ++k) {
        float4 a = At4[k * (AT_STRIDE / 4) + rq];
        float4 b = Wv4[k * 64 + jq];
        MK16(acc, a, b)
    }
    const int j4 = jq * 4;
    const int head = j4 >> 5;
    const int hdq = (j4 & 31) >> 2;           // float4 index within head
    float4 bias = ((const float4*)bv)[jq];
#pragma unroll
    for (int rr = 0; rr < 4; ++rr) {
        int hw = hw0 + rq * 4 + rr;
        float4 o = make_float4(acc[rr][0] + bias.x, acc[rr][1] + bias.y,
                               acc[rr][2] + bias.z, acc[rr][3] + bias.w);
        ((float4*)vh)[((cam * HEADS_ + head) * HWV + hw) * (HD_ / 4) + hdq] = o;
    }
}

// K2: gather q_reb rows (nearest, align_corners=True), GEMM vs Wcomb (N=192),
//     write off (+boff) and softmaxed attention weights.
__global__ __launch_bounds__(192) void k2_offatt(const float* __restrict__ query,
                                                 const float* __restrict__ qpos,
                                                 const float* __restrict__ qgrid,
                                                 const float* __restrict__ Wcomb,
                                                 const float* __restrict__ boff,
                                                 const float* __restrict__ batt,
                                                 float* __restrict__ off_ws,
                                                 float* __restrict__ att_ws) {
    __shared__ __align__(16) float At[CDIM * AT_STRIDE];
    __shared__ __align__(16) float res[16 * 192];
    __shared__ int rowpos[16];
    const int m0 = blockIdx.x * 16;           // m = cam*4000 + n, never crosses cam
    if (threadIdx.x < 16) {
        int m = m0 + threadIdx.x;
        float gx = qgrid[m * 2 + 0], gy = qgrid[m * 2 + 1];
        float fx = rintf(__fmul_rn(__fmul_rn(__fadd_rn(gx, 1.0f), 0.5f), (float)(BW_ - 1)));
        float fy = rintf(__fmul_rn(__fmul_rn(__fadd_rn(gy, 1.0f), 0.5f), (float)(BH_ - 1)));
        bool valid = (fx >= 0.0f) && (fx <= (float)(BW_ - 1)) && (fy >= 0.0f) && (fy <= (float)(BH_ - 1));
        rowpos[threadIdx.x] = valid ? ((int)fy * BW_ + (int)fx) : -1;
    }
    __syncthreads();
    for (int idx = threadIdx.x; idx < 16 * CDIM; idx += 192) {
        int r = idx >> 8, c = idx & 255;
        int p = rowpos[r];
        At[c * AT_STRIDE + r] = (p >= 0) ? (query[p * CDIM + c] + qpos[p * CDIM + c]) : 0.0f;
    }
    __syncthreads();
    const int rq = threadIdx.x / 48;          // 0..3
    const int jq = threadIdx.x % 48;          // 0..47
    float acc[4][4] = {};
    const float4* At4 = (const float4*)At;
    const float4* W4 = (const float4*)Wcomb;
#pragma unroll 4
    for (int k = 0; k < CDIM; ++k) {
        float4 a = At4[k * (AT_STRIDE / 4) + rq];
        float4 b = W4[k * 48 + jq];
        MK16(acc, a, b)
    }
    float4* res4 = (float4*)res;
#pragma unroll
    for (int rr = 0; rr < 4; ++rr)
        res4[(rq * 4 + rr) * 48 + jq] = make_float4(acc[rr][0], acc[rr][1], acc[rr][2], acc[rr][3]);
    __syncthreads();
    // offsets: 16 rows x 128 cols (+boff)
    for (int idx = threadIdx.x; idx < 16 * 128; idx += 192) {
        int r = idx >> 7, c = idx & 127;
        off_ws[(m0 + r) * 128 + c] = res[r * 192 + c] + boff[c];
    }
    // attention: softmax over PTS per (row, head)
    if (threadIdx.x < 128) {
        int r = threadIdx.x >> 3, h = threadIdx.x & 7;
        float v[PTS_];
        float mx = -1e30f;
#pragma unroll
        for (int p = 0; p < PTS_; ++p) {
            v[p] = res[r * 192 + 128 + h * 8 + p] + batt[h * 8 + p];
            mx = fmaxf(mx, v[p]);
        }
        float s = 0.0f;
#pragma unroll
        for (int p = 0; p < PTS_; ++p) { v[p] = expf(v[p] - mx); s += v[p]; }
        float inv = 1.0f / s;
#pragma unroll
        for (int p = 0; p < PTS_; ++p)
            att_ws[(m0 + r) * 64 + h * 8 + p] = v[p] * inv;
    }
}

// K3: bilinear deformable sampling + attention-weighted sum.
// One 32-lane group per (cam,n,head); lane = hd channel.
__global__ __launch_bounds__(256) void k3_sample(const float* __restrict__ vh,
                                                 const float* __restrict__ refp,
                                                 const float* __restrict__ off_ws,
                                                 const float* __restrict__ att_ws,
                                                 float* __restrict__ out_attn) {
    const int u = blockIdx.x * 8 + (threadIdx.x >> 5);   // (cam*4000+n)*8 + h, < 192000
    const int hd = threadIdx.x & 31;
    const int m = u >> 3;
    const int h = u & 7;
    const int cam = m / NQ_;
    const float rx = refp[m * 2 + 0];
    const float ry = refp[m * 2 + 1];
    const float* base = vh + (size_t)((cam * HEADS_ + h) * HWV) * HD_;
    const float4* off4 = (const float4*)(off_ws + m * 128 + h * 16);
    const float4* att4 = (const float4*)(att_ws + m * 64 + h * 8);
    float4 o0 = off4[0], o1 = off4[1], o2 = off4[2], o3 = off4[3];
    float4 a0 = att4[0], a1 = att4[1];
    float offv[16] = {o0.x, o0.y, o0.z, o0.w, o1.x, o1.y, o1.z, o1.w,
                      o2.x, o2.y, o2.z, o2.w, o3.x, o3.y, o3.z, o3.w};
    float attv[8] = {a0.x, a0.y, a0.z, a0.w, a1.x, a1.y, a1.z, a1.w};
    float acc = 0.0f;
#pragma unroll
    for (int p = 0; p < PTS_; ++p) {
        // loc = ref + off/norm; coord = loc*dim - 0.5  (continuous in off, fast form ok)
        float ax = rx * (float)WF_ + offv[p * 2 + 0] - 0.5f;
        float ay = ry * (float)HF_ + offv[p * 2 + 1] - 0.5f;
        float x0f = floorf(ax), y0f = floorf(ay);
        float wx = ax - x0f, wy = ay - y0f;
        int x0 = (int)x0f, y0 = (int)y0f;
        int x1 = x0 + 1, y1 = y0 + 1;
        bool vx0 = (x0 >= 0) && (x0 < WF_), vx1 = (x1 >= 0) && (x1 < WF_);
        bool vy0 = (y0 >= 0) && (y0 < HF_), vy1 = (y1 >= 0) && (y1 < HF_);
        int cx0 = min(max(x0, 0), WF_ - 1), cx1 = min(max(x1, 0), WF_ - 1);
        int cy0 = min(max(y0, 0), HF_ - 1), cy1 = min(max(y1, 0), HF_ - 1);
        float v00 = (vx0 && vy0) ? base[(cy0 * WF_ + cx0) * HD_ + hd] : 0.0f;
        float v01 = (vx1 && vy0) ? base[(cy0 * WF_ + cx1) * HD_ + hd] : 0.0f;
        float v10 = (vx0 && vy1) ? base[(cy1 * WF_ + cx0) * HD_ + hd] : 0.0f;
        float v11 = (vx1 && vy1) ? base[(cy1 * WF_ + cx1) * HD_ + hd] : 0.0f;
        float bil = (v00 * (1.0f - wx) + v01 * wx) * (1.0f - wy)
                  + (v10 * (1.0f - wx) + v11 * wx) * wy;
        acc += attv[p] * bil;
    }
    out_attn[m * CDIM + h * HD_ + hd] = acc;
}

// K4: restore-BEV nearest gather (sum of 2 overlap copies) * pillar_counts,
//     fused into output GEMM A-staging; out = s@Wout + bout + query.
__global__ __launch_bounds__(256) void k4_restore(const float* __restrict__ out_attn,
                                                  const float* __restrict__ rgrid,
                                                  const float* __restrict__ counts,
                                                  const float* __restrict__ Wout,
                                                  const float* __restrict__ bout,
                                                  const float* __restrict__ query,
                                                  float* __restrict__ out) {
    __shared__ __align__(16) float At[CDIM * AT_STRIDE];
    __shared__ int pos2[16][2];
    __shared__ float cnt[16];
    const int m0 = blockIdx.x * 16;           // output row i = bh*100 + bw
    if (threadIdx.x < 32) {
        int r = threadIdx.x >> 1, k = threadIdx.x & 1;
        int i = m0 + r;
        int bh = i / 100, bw = i - bh * 100;
        int R = bh + k * BH_;
        float gx = rgrid[(R * 100 + bw) * 2 + 0], gy = rgrid[(R * 100 + bw) * 2 + 1];
        float fx = rintf(__fmul_rn(__fmul_rn(__fadd_rn(gx, 1.0f), 0.5f), 39.0f));
        float fy = rintf(__fmul_rn(__fmul_rn(__fadd_rn(gy, 1.0f), 0.5f), 599.0f));
        bool valid = (fx >= 0.0f) && (fx <= 39.0f) && (fy >= 0.0f) && (fy <= 599.0f);
        int ix = (int)fx, iy = (int)fy;
        int camr = iy / 100, hg = iy - camr * 100;
        pos2[r][k] = valid ? (camr * NQ_ + hg * WG_ + ix) : -1;
        if (k == 0) cnt[r] = counts[i];
    }
    __syncthreads();
    for (int idx = threadIdx.x; idx < 16 * CDIM; idx += 256) {
        int r = idx >> 8, c = idx & 255;
        int p0 = pos2[r][0], p1 = pos2[r][1];
        float v = 0.0f;
        if (p0 >= 0) v += out_attn[p0 * CDIM + c];
        if (p1 >= 0) v += out_attn[p1 * CDIM + c];
        At[c * AT_STRIDE + r] = v * cnt[r];
    }
    __syncthreads();
    const int rq = threadIdx.x >> 6;
    const int jq = threadIdx.x & 63;
    float acc[4][4] = {};
    const float4* At4 = (const float4*)At;
    const float4* W4 = (const float4*)Wout;
#pragma unroll 4
    for (int k = 0; k < CDIM; ++k) {
        float4 a = At4[k * (AT_STRIDE / 4) + rq];
        float4 b = W4[k * 64 + jq];
        MK16(acc, a, b)
    }
    float4 bias = ((const float4*)bout)[jq];
#pragma unroll
    for (int rr = 0; rr < 4; ++rr) {
        int i = m0 + rq * 4 + rr;
        float4 qv = ((const float4*)query)[i * 64 + jq];
        float4 o = make_float4(acc[rr][0] + bias.x + qv.x, acc[rr][1] + bias.y + qv.y,
                               acc[rr][2] + bias.z + qv.z, acc[rr][3] + bias.w + qv.w);
        ((float4*)out)[i * 64 + jq] = o;
    }
}

extern "C" void kernel_launch(void* const* d_in, const int* in_sizes, int n_in,
                              void* d_out, int out_size, void* d_ws, size_t ws_size,
                              hipStream_t stream) {
    (void)in_sizes; (void)n_in; (void)out_size; (void)ws_size;
    const float* query  = (const float*)d_in[0];
    const float* value  = (const float*)d_in[1];
    const float* qgrid  = (const float*)d_in[2];
    const float* rgrid  = (const float*)d_in[3];
    const float* refp   = (const float*)d_in[4];
    const float* counts = (const float*)d_in[5];
    const float* qpos   = (const float*)d_in[6];
    const float* Wv     = (const float*)d_in[7];
    const float* bv     = (const float*)d_in[8];
    const float* Woff   = (const float*)d_in[9];
    const float* boff   = (const float*)d_in[10];
    const float* Watt   = (const float*)d_in[11];
    const float* batt   = (const float*)d_in[12];
    const float* Wout   = (const float*)d_in[13];
    const float* bout   = (const float*)d_in[14];
    float* out = (float*)d_out;
    float* ws  = (float*)d_ws;

    float* vh       = ws;                    // 6*8*3840*32      = 5,898,240 f
    float* out_attn = ws + 5898240;          // 24000*256        = 6,144,000 f
    float* att_ws   = ws + 12042240;         // 24000*64         = 1,536,000 f
    float* off_ws   = ws + 13578240;         // 24000*128        = 3,072,000 f
    float* Wcomb    = ws + 16650240;         // 256*192          =    49,152 f
                                             // total 16,699,392 f = 63.7 MiB

    hipLaunchKernelGGL(k0_wcomb,   dim3(192),   dim3(256), 0, stream, Woff, Watt, Wcomb);
    hipLaunchKernelGGL(k1_vproj,   dim3(M1_/16), dim3(256), 0, stream, value, Wv, bv, vh);
    hipLaunchKernelGGL(k2_offatt,  dim3(M2_/16), dim3(192), 0, stream, query, qpos, qgrid, Wcomb,
                       boff, batt, off_ws, att_ws);
    hipLaunchKernelGGL(k3_sample,  dim3(24000), dim3(256), 0, stream, vh, refp, off_ws, att_ws, out_attn);
    hipLaunchKernelGGL(k4_restore, dim3(NOUT_/16), dim3(256), 0, stream, out_attn, rgrid, counts,
                       Wout, bout, query, out);
}